// Round 12
// baseline (66.849 us; speedup 1.0000x reference)
//
#include <hip/hip_runtime.h>
#include <math.h>

#define KPTS 133
#define FPS  (KPTS * 3)          // 399 floats per sample
#define SPB  16                  // samples per block
#define SPWV 4                   // samples per wave (16 lanes each)

// DPP quad_perm shuffles: VALU-only (no LDS pipe, no lgkmcnt latency)
#define DPP_XOR1(x) __int_as_float(__builtin_amdgcn_update_dpp(0, __float_as_int(x), 0xB1, 0xF, 0xF, true))
#define DPP_XOR2(x) __int_as_float(__builtin_amdgcn_update_dpp(0, __float_as_int(x), 0x4E, 0xF, 0xF, true))

__device__ __forceinline__ float2 f2(float a, float b) { return make_float2(a, b); }

__device__ __forceinline__ float det3(float a0, float a1, float a2,
                                      float b0, float b1, float b2,
                                      float c0, float c1, float c2) {
    return a0 * (b1 * c2 - b2 * c1)
         - a1 * (b0 * c2 - b2 * c0)
         + a2 * (b0 * c1 - b1 * c0);
}

// R12 = R11 structure WITHOUT the staging LDS:
//  - points read directly from global in both passes (stride-12B lanes are
//    CONTIGUOUS coverage -> dense dwordx3 coalescing; 2nd pass is L1/L2-hot).
//  - LDS = 2KB (moment tile + params) -> occupancy 12 -> 28 waves/CU.
//  - LDS pipe & 3.7M bank-conflict cycles eliminated; HBM becomes the cap.
__global__ __launch_bounds__(256, 7) void pa_mpjpe_kernel(
    const float* __restrict__ outp,   // (N,K,3) output
    const float* __restrict__ tgtp,   // (N,K,3) target
    float* __restrict__ block_sums,
    int nsamp)
{
    const int tid  = threadIdx.x;
    const int lane = tid & 63;
    const int wid  = tid >> 6;
    const int l16  = lane & 15;
    const int s_l  = wid * SPWV + (lane >> 4);   // local sample 0..15
    int s = blockIdx.x * SPB + s_l;
    const bool valid = (s < nsamp);
    if (!valid) s = 0;                           // clamp; zeroed later

    __shared__ float momT[SPB][17];
    __shared__ float prm[SPB][13];
    __shared__ float shs[SPB];

    const float* tb = tgtp + (size_t)s * FPS;
    const float* ob = outp + (size_t)s * FPS;

    // ---- moments: packed-f32 accumulation, 9 float2 FMAs per point ----
    float2 P0 = f2(0,0), P1 = f2(0,0), P2 = f2(0,0), P3 = f2(0,0);
    float2 P4 = f2(0,0), P5 = f2(0,0), P6 = f2(0,0), P7 = f2(0,0);
    float2 Q  = f2(0,0);

#define PA_ACC(t0, t1, t2, o0, o1, o2)          \
    P0 += f2(t0, t1);                           \
    P1 += f2(t2, o0);                           \
    P2 += f2(o1, o2);                           \
    P3 += f2(t0, t0) * f2(o0, o1);              \
    P4 += f2(t0, t1) * f2(o2, o0);              \
    P5 += f2(t1, t1) * f2(o1, o2);              \
    P6 += f2(t2, t2) * f2(o0, o1);              \
    P7 += f2(t2, t0) * f2(o2, t0);              \
    Q  += f2(t1, t2) * f2(t1, t2);

    #pragma unroll
    for (int k = 0; k < 8; ++k) {
        const int idx = 3 * (l16 + 16 * k);
        const float t0 = tb[idx + 0], t1 = tb[idx + 1], t2 = tb[idx + 2];
        const float o0 = ob[idx + 0], o1 = ob[idx + 1], o2 = ob[idx + 2];
        PA_ACC(t0, t1, t2, o0, o1, o2)
    }
    if (l16 < 5) {
        const int idx = 3 * (128 + l16);
        const float t0 = tb[idx + 0], t1 = tb[idx + 1], t2 = tb[idx + 2];
        const float o0 = ob[idx + 0], o1 = ob[idx + 1], o2 = ob[idx + 2];
        PA_ACC(t0, t1, t2, o0, o1, o2)
    }
#undef PA_ACC

    float red[16];
    red[0]  = P0.x; red[1]  = P0.y; red[2]  = P1.x; red[3]  = P1.y;
    red[4]  = P2.x; red[5]  = P2.y; red[6]  = P3.x; red[7]  = P3.y;
    red[8]  = P4.x; red[9]  = P4.y; red[10] = P5.x; red[11] = P5.y;
    red[12] = P6.x; red[13] = P6.y; red[14] = P7.x; red[15] = P7.y + Q.x + Q.y;

    // ---- 4-stage value-splitting butterfly within 16-lane group ----
    float v8[8];
    {
        const bool b = (lane & 1);
        #pragma unroll
        for (int m = 0; m < 8; ++m) {
            const float snd = b ? red[2 * m] : red[2 * m + 1];
            const float rcv = DPP_XOR1(snd);
            v8[m] = (b ? red[2 * m + 1] : red[2 * m]) + rcv;
        }
    }
    float v4_[4];
    {
        const bool b = ((lane >> 1) & 1);
        #pragma unroll
        for (int m = 0; m < 4; ++m) {
            const float snd = b ? v8[2 * m] : v8[2 * m + 1];
            const float rcv = DPP_XOR2(snd);
            v4_[m] = (b ? v8[2 * m + 1] : v8[2 * m]) + rcv;
        }
    }
    float v2_[2];
    {
        const bool b = ((lane >> 2) & 1);
        #pragma unroll
        for (int m = 0; m < 2; ++m) {
            const float snd = b ? v4_[2 * m] : v4_[2 * m + 1];
            const float rcv = __shfl_xor(snd, 4, 64);
            v2_[m] = (b ? v4_[2 * m + 1] : v4_[2 * m]) + rcv;
        }
    }
    float v1;
    {
        const bool b = ((lane >> 3) & 1);
        const float snd = b ? v2_[0] : v2_[1];
        const float rcv = __shfl_xor(snd, 8, 64);
        v1 = (b ? v2_[1] : v2_[0]) + rcv;
    }

    momT[s_l][l16] = v1;
    __syncthreads();

    // ---- solve: wave 0, lanes 0..15, one sample each (16x amortized) ----
    if (wid == 0 && lane < SPB && (blockIdx.x * SPB + lane) < nsamp) {
        float m_[16];
        #pragma unroll
        for (int j = 0; j < 16; ++j) m_[j] = momT[lane][j];

        const float invK = 1.0f / (float)KPTS;
        const float mu1x = m_[0] * invK, mu1y = m_[1] * invK, mu1z = m_[2] * invK;
        const float mu2x = m_[3] * invK, mu2y = m_[4] * invK, mu2z = m_[5] * invK;

        const float Sxx = m_[6]  - m_[0] * m_[3] * invK;
        const float Sxy = m_[7]  - m_[0] * m_[4] * invK;
        const float Sxz = m_[8]  - m_[0] * m_[5] * invK;
        const float Syx = m_[9]  - m_[1] * m_[3] * invK;
        const float Syy = m_[10] - m_[1] * m_[4] * invK;
        const float Syz = m_[11] - m_[1] * m_[5] * invK;
        const float Szx = m_[12] - m_[2] * m_[3] * invK;
        const float Szy = m_[13] - m_[2] * m_[4] * invK;
        const float Szz = m_[14] - m_[2] * m_[5] * invK;
        const float var1 = m_[15] - (m_[0] * m_[0] + m_[1] * m_[1] + m_[2] * m_[2]) * invK;

        const float N00 = Sxx + Syy + Szz;
        const float N01 = Syz - Szy, N02 = Szx - Sxz, N03 = Sxy - Syx;
        const float N11 = Sxx - Syy - Szz, N12 = Sxy + Syx, N13 = Szx + Sxz;
        const float N22 = -Sxx + Syy - Szz, N23 = Syz + Szy;
        const float N33 = -Sxx - Syy + Szz;

        const float trKtK = Sxx * Sxx + Sxy * Sxy + Sxz * Sxz
                          + Syx * Syx + Syy * Syy + Syz * Syz
                          + Szx * Szx + Szy * Szy + Szz * Szz;
        const float c2 = -2.0f * trKtK;
        const float detK = det3(Sxx, Sxy, Sxz, Syx, Syy, Syz, Szx, Szy, Szz);
        const float c1 = -8.0f * detK;
        const float c0 =
              N00 * det3(N11, N12, N13, N12, N22, N23, N13, N23, N33)
            - N01 * det3(N01, N12, N13, N02, N22, N23, N03, N23, N33)
            + N02 * det3(N01, N11, N13, N02, N12, N23, N03, N13, N33)
            - N03 * det3(N01, N11, N12, N02, N12, N22, N03, N13, N23);

        float lam = sqrtf(fmaxf(3.0f * trKtK, 0.0f));
        #pragma unroll
        for (int it = 0; it < 10; ++it) {
            const float l2 = lam * lam;
            const float P  = (l2 + c2) * l2 + c1 * lam + c0;
            const float Pp = (4.0f * l2 + 2.0f * c2) * lam + c1;
            lam -= P / Pp;
        }

        const float M00 = N00 - lam, M11 = N11 - lam, M22 = N22 - lam, M33 = N33 - lam;
        const float a0 =  det3(M11, N12, N13, N12, M22, N23, N13, N23, M33);
        const float a1 = -det3(N01, N12, N13, N02, M22, N23, N03, N23, M33);
        const float a2 =  det3(N01, M11, N13, N02, N12, N23, N03, N13, M33);
        const float a3 = -det3(N01, M11, N12, N02, N12, M22, N03, N13, N23);
        const float b0 = -det3(N01, N02, N03, N12, M22, N23, N13, N23, M33);
        const float b1 =  det3(M00, N02, N03, N02, M22, N23, N03, N23, M33);
        const float b2 = -det3(M00, N01, N03, N02, N12, N23, N03, N13, M33);
        const float b3 =  det3(M00, N01, N02, N02, N12, M22, N03, N13, N23);
        const float na = a0 * a0 + a1 * a1 + a2 * a2 + a3 * a3;
        const float nb = b0 * b0 + b1 * b1 + b2 * b2 + b3 * b3;
        const bool pa_ = (na >= nb);
        float qw = pa_ ? a0 : b0;
        float qx = pa_ ? a1 : b1;
        float qy = pa_ ? a2 : b2;
        float qz = pa_ ? a3 : b3;
        const float qn = rsqrtf(fmaxf(qw * qw + qx * qx + qy * qy + qz * qz, 1e-30f));
        qw *= qn; qx *= qn; qy *= qn; qz *= qn;

        const float R00 = 1.0f - 2.0f * (qy * qy + qz * qz);
        const float R01 = 2.0f * (qx * qy - qw * qz);
        const float R02 = 2.0f * (qx * qz + qw * qy);
        const float R10 = 2.0f * (qx * qy + qw * qz);
        const float R11 = 1.0f - 2.0f * (qx * qx + qz * qz);
        const float R12 = 2.0f * (qy * qz - qw * qx);
        const float R20 = 2.0f * (qx * qz - qw * qy);
        const float R21 = 2.0f * (qy * qz + qw * qx);
        const float R22 = 1.0f - 2.0f * (qx * qx + qy * qy);

        const float trRK = R00 * Sxx + R01 * Syx + R02 * Szx
                         + R10 * Sxy + R11 * Syy + R12 * Szy
                         + R20 * Sxz + R21 * Syz + R22 * Szz;
        const float scale = trRK / var1;

        const float tx = mu2x - scale * (R00 * mu1x + R01 * mu1y + R02 * mu1z);
        const float ty = mu2y - scale * (R10 * mu1x + R11 * mu1y + R12 * mu1z);
        const float tz = mu2z - scale * (R20 * mu1x + R21 * mu1y + R22 * mu1z);

        prm[lane][0] = scale * R00; prm[lane][1] = scale * R01; prm[lane][2] = scale * R02;
        prm[lane][3] = scale * R10; prm[lane][4] = scale * R11; prm[lane][5] = scale * R12;
        prm[lane][6] = scale * R20; prm[lane][7] = scale * R21; prm[lane][8] = scale * R22;
        prm[lane][9] = tx; prm[lane][10] = ty; prm[lane][11] = tz;
    }
    __syncthreads();

    // ---- residuals: packed-f32 transform, global re-read (L1/L2-hot) ----
    const float2 rA = f2(prm[s_l][0], prm[s_l][3]);   // (sR00, sR10)
    const float2 rB = f2(prm[s_l][1], prm[s_l][4]);   // (sR01, sR11)
    const float2 rC = f2(prm[s_l][2], prm[s_l][5]);   // (sR02, sR12)
    const float sR20 = prm[s_l][6], sR21 = prm[s_l][7], sR22 = prm[s_l][8];
    const float2 txy = f2(prm[s_l][9], prm[s_l][10]);
    const float tz = prm[s_l][11];

    float rsum = 0.0f;
#define PA_RES(t0, t1, t2, o0, o1, o2)                                     \
    {                                                                      \
        float2 axy = txy;                                                  \
        axy += rA * f2(t0, t0);                                            \
        axy += rB * f2(t1, t1);                                            \
        axy += rC * f2(t2, t2);                                            \
        const float az = fmaf(sR20, (t0), fmaf(sR21, (t1), fmaf(sR22, (t2), tz))); \
        const float2 dxy = f2(o0, o1) - axy;                               \
        const float dz = (o2) - az;                                        \
        const float ns = fmaf(dxy.x, dxy.x, fmaf(dxy.y, dxy.y, dz * dz));  \
        rsum += sqrtf(ns);                                                 \
    }
    #pragma unroll
    for (int k = 0; k < 8; ++k) {
        const int idx = 3 * (l16 + 16 * k);
        const float t0 = tb[idx + 0], t1 = tb[idx + 1], t2 = tb[idx + 2];
        const float o0 = ob[idx + 0], o1 = ob[idx + 1], o2 = ob[idx + 2];
        PA_RES(t0, t1, t2, o0, o1, o2)
    }
    if (l16 < 5) {
        const int idx = 3 * (128 + l16);
        const float t0 = tb[idx + 0], t1 = tb[idx + 1], t2 = tb[idx + 2];
        const float o0 = ob[idx + 0], o1 = ob[idx + 1], o2 = ob[idx + 2];
        PA_RES(t0, t1, t2, o0, o1, o2)
    }
#undef PA_RES

    rsum = valid ? rsum : 0.0f;

    rsum += DPP_XOR1(rsum);
    rsum += DPP_XOR2(rsum);
    rsum += __shfl_xor(rsum, 4, 64);
    rsum += __shfl_xor(rsum, 8, 64);

    if (l16 == 0) shs[s_l] = rsum;
    __syncthreads();
    if (tid == 0) {
        float b = 0.0f;
        #pragma unroll
        for (int i = 0; i < SPB; ++i) b += shs[i];
        block_sums[blockIdx.x] = b;
    }
}

// Deterministic final reduction: one block, fixed order, 4-way ILP.
__global__ __launch_bounds__(256) void pa_reduce_kernel(
    const float* __restrict__ block_sums, int n,
    float* __restrict__ out, float inv_total)
{
    __shared__ float sh[4];
    float a0 = 0.f, a1 = 0.f, a2 = 0.f, a3 = 0.f;
    for (int i = (int)threadIdx.x * 4; i < n; i += 1024) {
        if (i + 0 < n) a0 += block_sums[i + 0];
        if (i + 1 < n) a1 += block_sums[i + 1];
        if (i + 2 < n) a2 += block_sums[i + 2];
        if (i + 3 < n) a3 += block_sums[i + 3];
    }
    float v = (a0 + a1) + (a2 + a3);
    #pragma unroll
    for (int off = 32; off >= 1; off >>= 1) v += __shfl_xor(v, off, 64);
    const int lane = threadIdx.x & 63;
    const int wid  = threadIdx.x >> 6;
    if (lane == 0) sh[wid] = v;
    __syncthreads();
    if (threadIdx.x == 0) out[0] = (sh[0] + sh[1] + sh[2] + sh[3]) * inv_total;
}

extern "C" void kernel_launch(void* const* d_in, const int* in_sizes, int n_in,
                              void* d_out, int out_size, void* d_ws, size_t ws_size,
                              hipStream_t stream) {
    const float* outp = (const float*)d_in[0];   // "output"
    const float* tgtp = (const float*)d_in[1];   // "target"
    const int nsamp   = in_sizes[0] / FPS;
    const int nblocks = (nsamp + SPB - 1) / SPB;

    float* bsums = (float*)d_ws;

    pa_mpjpe_kernel<<<nblocks, 256, 0, stream>>>(outp, tgtp, bsums, nsamp);
    pa_reduce_kernel<<<1, 256, 0, stream>>>(
        bsums, nblocks, (float*)d_out,
        1.0f / ((float)nsamp * (float)KPTS));
}

// Round 13
// 55.200 us; speedup vs baseline: 1.2110x; 1.2110x over previous
//
#include <hip/hip_runtime.h>
#include <math.h>

#define KPTS 133
#define FPS  (KPTS * 3)          // 399 floats per sample
#define SPB  16                  // samples per block
#define SPWV 4                   // samples per wave (16 lanes each)
#define BLK_F4 ((SPB * FPS) / 4) // 1596 float4 per array per block (exact)

// DPP quad_perm shuffles: VALU-only (no LDS pipe, no lgkmcnt latency)
#define DPP_XOR1(x) __int_as_float(__builtin_amdgcn_update_dpp(0, __float_as_int(x), 0xB1, 0xF, 0xF, true))
#define DPP_XOR2(x) __int_as_float(__builtin_amdgcn_update_dpp(0, __float_as_int(x), 0x4E, 0xF, 0xF, true))

__device__ __forceinline__ float2 f2(float a, float b) { return make_float2(a, b); }

__device__ __forceinline__ float det3(float a0, float a1, float a2,
                                      float b0, float b1, float b2,
                                      float c0, float c1, float c2) {
    return a0 * (b1 * c2 - b2 * c1)
         - a1 * (b0 * c2 - b2 * c0)
         + a2 * (b0 * c1 - b1 * c0);
}

// R13 = R11 with the two read passes split across different pipes:
//  - MOMENT pass reads GLOBAL (the exact lines the staging loads just fetched
//    -> L1/L2-hot; uses the TA pipe, not LDS; needs no barrier, so staging
//    ds_writes drain underneath the moment+butterfly compute).
//  - RESIDUAL pass reads the LDS copy (guaranteed on-chip; the late pass is
//    the one that must not depend on cache survival -- R12's lesson).
//  LDS read traffic + bank conflicts halve; barriers 4 -> 3.
__global__ __launch_bounds__(256, 3) void pa_mpjpe_kernel(
    const float* __restrict__ outp,   // (N,K,3) output
    const float* __restrict__ tgtp,   // (N,K,3) target
    float* __restrict__ block_sums,
    int nsamp)
{
    const int tid  = threadIdx.x;
    const int lane = tid & 63;
    const int wid  = tid >> 6;
    const int l16  = lane & 15;
    const int s_l  = wid * SPWV + (lane >> 4);   // local sample 0..15
    int s = blockIdx.x * SPB + s_l;
    const bool valid = (s < nsamp);
    if (!valid) s = 0;                           // clamp; zeroed later

    __shared__ __align__(16) float tl[SPB * FPS];   // 25536 B
    __shared__ __align__(16) float ol[SPB * FPS];   // 25536 B
    __shared__ float momT[SPB][17];
    __shared__ float prm[SPB][13];
    __shared__ float shs[SPB];

    const float* tb = tgtp + (size_t)s * FPS;
    const float* ob = outp + (size_t)s * FPS;

    // ---- stage: aligned float4 global -> LDS (writes drain during moments) ----
    {
        const long blk_f4 = (long)blockIdx.x * BLK_F4;
        const long nfl    = (long)nsamp * FPS;
        const float4* tg4 = (const float4*)tgtp;
        const float4* og4 = (const float4*)outp;
        float4* tl4 = (float4*)tl;
        float4* ol4 = (float4*)ol;
        #pragma unroll
        for (int r = 0; r < 7; ++r) {
            const int i = tid + 256 * r;
            if (i < BLK_F4) {
                const long g4 = blk_f4 + i;
                if ((g4 + 1) * 4 <= nfl) {
                    tl4[i] = tg4[g4];
                    ol4[i] = og4[g4];
                } else {
                    #pragma unroll
                    for (int c = 0; c < 4; ++c) {
                        const long g = g4 * 4 + c;
                        float tv = 0.f, ov = 0.f;
                        if (g < nfl) { tv = tgtp[g]; ov = outp[g]; }
                        tl[i * 4 + c] = tv;
                        ol[i * 4 + c] = ov;
                    }
                }
            }
        }
    }
    // NO barrier here: moment pass reads global (independent of LDS writes).

    // ---- moments from GLOBAL (L1/L2-hot: same lines staging just loaded) ----
    float2 P0 = f2(0,0), P1 = f2(0,0), P2 = f2(0,0), P3 = f2(0,0);
    float2 P4 = f2(0,0), P5 = f2(0,0), P6 = f2(0,0), P7 = f2(0,0);
    float2 Q  = f2(0,0);

#define PA_ACC(t0, t1, t2, o0, o1, o2)          \
    P0 += f2(t0, t1);                           \
    P1 += f2(t2, o0);                           \
    P2 += f2(o1, o2);                           \
    P3 += f2(t0, t0) * f2(o0, o1);              \
    P4 += f2(t0, t1) * f2(o2, o0);              \
    P5 += f2(t1, t1) * f2(o1, o2);              \
    P6 += f2(t2, t2) * f2(o0, o1);              \
    P7 += f2(t2, t0) * f2(o2, t0);              \
    Q  += f2(t1, t2) * f2(t1, t2);

    #pragma unroll
    for (int k = 0; k < 8; ++k) {
        const int idx = 3 * (l16 + 16 * k);
        const float t0 = tb[idx + 0], t1 = tb[idx + 1], t2 = tb[idx + 2];
        const float o0 = ob[idx + 0], o1 = ob[idx + 1], o2 = ob[idx + 2];
        PA_ACC(t0, t1, t2, o0, o1, o2)
    }
    if (l16 < 5) {
        const int idx = 3 * (128 + l16);
        const float t0 = tb[idx + 0], t1 = tb[idx + 1], t2 = tb[idx + 2];
        const float o0 = ob[idx + 0], o1 = ob[idx + 1], o2 = ob[idx + 2];
        PA_ACC(t0, t1, t2, o0, o1, o2)
    }
#undef PA_ACC

    float red[16];
    red[0]  = P0.x; red[1]  = P0.y; red[2]  = P1.x; red[3]  = P1.y;
    red[4]  = P2.x; red[5]  = P2.y; red[6]  = P3.x; red[7]  = P3.y;
    red[8]  = P4.x; red[9]  = P4.y; red[10] = P5.x; red[11] = P5.y;
    red[12] = P6.x; red[13] = P6.y; red[14] = P7.x; red[15] = P7.y + Q.x + Q.y;

    // ---- 4-stage value-splitting butterfly within 16-lane group ----
    float v8[8];
    {
        const bool b = (lane & 1);
        #pragma unroll
        for (int m = 0; m < 8; ++m) {
            const float snd = b ? red[2 * m] : red[2 * m + 1];
            const float rcv = DPP_XOR1(snd);
            v8[m] = (b ? red[2 * m + 1] : red[2 * m]) + rcv;
        }
    }
    float v4_[4];
    {
        const bool b = ((lane >> 1) & 1);
        #pragma unroll
        for (int m = 0; m < 4; ++m) {
            const float snd = b ? v8[2 * m] : v8[2 * m + 1];
            const float rcv = DPP_XOR2(snd);
            v4_[m] = (b ? v8[2 * m + 1] : v8[2 * m]) + rcv;
        }
    }
    float v2_[2];
    {
        const bool b = ((lane >> 2) & 1);
        #pragma unroll
        for (int m = 0; m < 2; ++m) {
            const float snd = b ? v4_[2 * m] : v4_[2 * m + 1];
            const float rcv = __shfl_xor(snd, 4, 64);
            v2_[m] = (b ? v4_[2 * m + 1] : v4_[2 * m]) + rcv;
        }
    }
    float v1;
    {
        const bool b = ((lane >> 3) & 1);
        const float snd = b ? v2_[0] : v2_[1];
        const float rcv = __shfl_xor(snd, 8, 64);
        v1 = (b ? v2_[1] : v2_[0]) + rcv;
    }

    momT[s_l][l16] = v1;
    __syncthreads();   // barrier 1: staging writes + momT visible

    // ---- solve: wave 0, lanes 0..15, one sample each (16x amortized) ----
    if (wid == 0 && lane < SPB && (blockIdx.x * SPB + lane) < nsamp) {
        float m_[16];
        #pragma unroll
        for (int j = 0; j < 16; ++j) m_[j] = momT[lane][j];

        const float invK = 1.0f / (float)KPTS;
        const float mu1x = m_[0] * invK, mu1y = m_[1] * invK, mu1z = m_[2] * invK;
        const float mu2x = m_[3] * invK, mu2y = m_[4] * invK, mu2z = m_[5] * invK;

        const float Sxx = m_[6]  - m_[0] * m_[3] * invK;
        const float Sxy = m_[7]  - m_[0] * m_[4] * invK;
        const float Sxz = m_[8]  - m_[0] * m_[5] * invK;
        const float Syx = m_[9]  - m_[1] * m_[3] * invK;
        const float Syy = m_[10] - m_[1] * m_[4] * invK;
        const float Syz = m_[11] - m_[1] * m_[5] * invK;
        const float Szx = m_[12] - m_[2] * m_[3] * invK;
        const float Szy = m_[13] - m_[2] * m_[4] * invK;
        const float Szz = m_[14] - m_[2] * m_[5] * invK;
        const float var1 = m_[15] - (m_[0] * m_[0] + m_[1] * m_[1] + m_[2] * m_[2]) * invK;

        const float N00 = Sxx + Syy + Szz;
        const float N01 = Syz - Szy, N02 = Szx - Sxz, N03 = Sxy - Syx;
        const float N11 = Sxx - Syy - Szz, N12 = Sxy + Syx, N13 = Szx + Sxz;
        const float N22 = -Sxx + Syy - Szz, N23 = Syz + Szy;
        const float N33 = -Sxx - Syy + Szz;

        const float trKtK = Sxx * Sxx + Sxy * Sxy + Sxz * Sxz
                          + Syx * Syx + Syy * Syy + Syz * Syz
                          + Szx * Szx + Szy * Szy + Szz * Szz;
        const float c2 = -2.0f * trKtK;
        const float detK = det3(Sxx, Sxy, Sxz, Syx, Syy, Syz, Szx, Szy, Szz);
        const float c1 = -8.0f * detK;
        const float c0 =
              N00 * det3(N11, N12, N13, N12, N22, N23, N13, N23, N33)
            - N01 * det3(N01, N12, N13, N02, N22, N23, N03, N23, N33)
            + N02 * det3(N01, N11, N13, N02, N12, N23, N03, N13, N33)
            - N03 * det3(N01, N11, N12, N02, N12, N22, N03, N13, N23);

        float lam = sqrtf(fmaxf(3.0f * trKtK, 0.0f));
        #pragma unroll
        for (int it = 0; it < 10; ++it) {
            const float l2 = lam * lam;
            const float P  = (l2 + c2) * l2 + c1 * lam + c0;
            const float Pp = (4.0f * l2 + 2.0f * c2) * lam + c1;
            lam -= P / Pp;
        }

        const float M00 = N00 - lam, M11 = N11 - lam, M22 = N22 - lam, M33 = N33 - lam;
        const float a0 =  det3(M11, N12, N13, N12, M22, N23, N13, N23, M33);
        const float a1 = -det3(N01, N12, N13, N02, M22, N23, N03, N23, M33);
        const float a2 =  det3(N01, M11, N13, N02, N12, N23, N03, N13, M33);
        const float a3 = -det3(N01, M11, N12, N02, N12, M22, N03, N13, N23);
        const float b0 = -det3(N01, N02, N03, N12, M22, N23, N13, N23, M33);
        const float b1 =  det3(M00, N02, N03, N02, M22, N23, N03, N23, M33);
        const float b2 = -det3(M00, N01, N03, N02, N12, N23, N03, N13, M33);
        const float b3 =  det3(M00, N01, N02, N02, N12, M22, N03, N13, N23);
        const float na = a0 * a0 + a1 * a1 + a2 * a2 + a3 * a3;
        const float nb = b0 * b0 + b1 * b1 + b2 * b2 + b3 * b3;
        const bool pa_ = (na >= nb);
        float qw = pa_ ? a0 : b0;
        float qx = pa_ ? a1 : b1;
        float qy = pa_ ? a2 : b2;
        float qz = pa_ ? a3 : b3;
        const float qn = rsqrtf(fmaxf(qw * qw + qx * qx + qy * qy + qz * qz, 1e-30f));
        qw *= qn; qx *= qn; qy *= qn; qz *= qn;

        const float R00 = 1.0f - 2.0f * (qy * qy + qz * qz);
        const float R01 = 2.0f * (qx * qy - qw * qz);
        const float R02 = 2.0f * (qx * qz + qw * qy);
        const float R10 = 2.0f * (qx * qy + qw * qz);
        const float R11 = 1.0f - 2.0f * (qx * qx + qz * qz);
        const float R12 = 2.0f * (qy * qz - qw * qx);
        const float R20 = 2.0f * (qx * qz - qw * qy);
        const float R21 = 2.0f * (qy * qz + qw * qx);
        const float R22 = 1.0f - 2.0f * (qx * qx + qy * qy);

        const float trRK = R00 * Sxx + R01 * Syx + R02 * Szx
                         + R10 * Sxy + R11 * Syy + R12 * Szy
                         + R20 * Sxz + R21 * Syz + R22 * Szz;
        const float scale = trRK / var1;

        const float tx = mu2x - scale * (R00 * mu1x + R01 * mu1y + R02 * mu1z);
        const float ty = mu2y - scale * (R10 * mu1x + R11 * mu1y + R12 * mu1z);
        const float tz = mu2z - scale * (R20 * mu1x + R21 * mu1y + R22 * mu1z);

        prm[lane][0] = scale * R00; prm[lane][1] = scale * R01; prm[lane][2] = scale * R02;
        prm[lane][3] = scale * R10; prm[lane][4] = scale * R11; prm[lane][5] = scale * R12;
        prm[lane][6] = scale * R20; prm[lane][7] = scale * R21; prm[lane][8] = scale * R22;
        prm[lane][9] = tx; prm[lane][10] = ty; prm[lane][11] = tz;
    }
    __syncthreads();   // barrier 2

    // ---- residuals from the LDS copy (on-chip by construction) ----
    const float* tw = tl + s_l * FPS;
    const float* ow = ol + s_l * FPS;

    const float2 rA = f2(prm[s_l][0], prm[s_l][3]);   // (sR00, sR10)
    const float2 rB = f2(prm[s_l][1], prm[s_l][4]);   // (sR01, sR11)
    const float2 rC = f2(prm[s_l][2], prm[s_l][5]);   // (sR02, sR12)
    const float sR20 = prm[s_l][6], sR21 = prm[s_l][7], sR22 = prm[s_l][8];
    const float2 txy = f2(prm[s_l][9], prm[s_l][10]);
    const float tz = prm[s_l][11];

    float rsum = 0.0f;
#define PA_RES(t0, t1, t2, o0, o1, o2)                                     \
    {                                                                      \
        float2 axy = txy;                                                  \
        axy += rA * f2(t0, t0);                                            \
        axy += rB * f2(t1, t1);                                            \
        axy += rC * f2(t2, t2);                                            \
        const float az = fmaf(sR20, (t0), fmaf(sR21, (t1), fmaf(sR22, (t2), tz))); \
        const float2 dxy = f2(o0, o1) - axy;                               \
        const float dz = (o2) - az;                                        \
        const float ns = fmaf(dxy.x, dxy.x, fmaf(dxy.y, dxy.y, dz * dz));  \
        rsum += sqrtf(ns);                                                 \
    }
    #pragma unroll
    for (int k = 0; k < 8; ++k) {
        const int idx = 3 * (l16 + 16 * k);
        const float t0 = tw[idx + 0], t1 = tw[idx + 1], t2 = tw[idx + 2];
        const float o0 = ow[idx + 0], o1 = ow[idx + 1], o2 = ow[idx + 2];
        PA_RES(t0, t1, t2, o0, o1, o2)
    }
    if (l16 < 5) {
        const int idx = 3 * (128 + l16);
        const float t0 = tw[idx + 0], t1 = tw[idx + 1], t2 = tw[idx + 2];
        const float o0 = ow[idx + 0], o1 = ow[idx + 1], o2 = ow[idx + 2];
        PA_RES(t0, t1, t2, o0, o1, o2)
    }
#undef PA_RES

    rsum = valid ? rsum : 0.0f;

    rsum += DPP_XOR1(rsum);
    rsum += DPP_XOR2(rsum);
    rsum += __shfl_xor(rsum, 4, 64);
    rsum += __shfl_xor(rsum, 8, 64);

    if (l16 == 0) shs[s_l] = rsum;
    __syncthreads();   // barrier 3
    if (tid == 0) {
        float b = 0.0f;
        #pragma unroll
        for (int i = 0; i < SPB; ++i) b += shs[i];
        block_sums[blockIdx.x] = b;
    }
}

// Deterministic final reduction: one block, fixed order, 4-way ILP.
__global__ __launch_bounds__(256) void pa_reduce_kernel(
    const float* __restrict__ block_sums, int n,
    float* __restrict__ out, float inv_total)
{
    __shared__ float sh[4];
    float a0 = 0.f, a1 = 0.f, a2 = 0.f, a3 = 0.f;
    for (int i = (int)threadIdx.x * 4; i < n; i += 1024) {
        if (i + 0 < n) a0 += block_sums[i + 0];
        if (i + 1 < n) a1 += block_sums[i + 1];
        if (i + 2 < n) a2 += block_sums[i + 2];
        if (i + 3 < n) a3 += block_sums[i + 3];
    }
    float v = (a0 + a1) + (a2 + a3);
    #pragma unroll
    for (int off = 32; off >= 1; off >>= 1) v += __shfl_xor(v, off, 64);
    const int lane = threadIdx.x & 63;
    const int wid  = threadIdx.x >> 6;
    if (lane == 0) sh[wid] = v;
    __syncthreads();
    if (threadIdx.x == 0) out[0] = (sh[0] + sh[1] + sh[2] + sh[3]) * inv_total;
}

extern "C" void kernel_launch(void* const* d_in, const int* in_sizes, int n_in,
                              void* d_out, int out_size, void* d_ws, size_t ws_size,
                              hipStream_t stream) {
    const float* outp = (const float*)d_in[0];   // "output"
    const float* tgtp = (const float*)d_in[1];   // "target"
    const int nsamp   = in_sizes[0] / FPS;
    const int nblocks = (nsamp + SPB - 1) / SPB;

    float* bsums = (float*)d_ws;

    pa_mpjpe_kernel<<<nblocks, 256, 0, stream>>>(outp, tgtp, bsums, nsamp);
    pa_reduce_kernel<<<1, 256, 0, stream>>>(
        bsums, nblocks, (float*)d_out,
        1.0f / ((float)nsamp * (float)KPTS));
}

// Round 14
// 43.123 us; speedup vs baseline: 1.5502x; 1.2801x over previous
//
#include <hip/hip_runtime.h>
#include <math.h>

#define KPTS 133
#define FPS  (KPTS * 3)          // 399 floats per sample
#define SPB  16                  // samples per block
#define SPWV 4                   // samples per wave (16 lanes each)

// DPP quad_perm shuffles: VALU-only (no LDS pipe, no lgkmcnt latency)
#define DPP_XOR1(x) __int_as_float(__builtin_amdgcn_update_dpp(0, __float_as_int(x), 0xB1, 0xF, 0xF, true))
#define DPP_XOR2(x) __int_as_float(__builtin_amdgcn_update_dpp(0, __float_as_int(x), 0x4E, 0xF, 0xF, true))

// Opaque register pin: forces the value to stay materialized in a VGPR and
// forbids the compiler from rematerializing the originating load (the asm
// "may have changed" the value, so later uses must consume THIS register).
#define PIN(x) asm volatile("" : "+v"(x))

__device__ __forceinline__ float2 f2(float a, float b) { return make_float2(a, b); }

__device__ __forceinline__ float det3(float a0, float a1, float a2,
                                      float b0, float b1, float b2,
                                      float c0, float c1, float c2) {
    return a0 * (b1 * c2 - b2 * c1)
         - a1 * (b0 * c2 - b2 * c0)
         + a2 * (b0 * c1 - b1 * c0);
}

// R14: ONE data pass. R11's proven shape (4 samples/wave, 16-lane groups,
// DPP butterfly, 16-lane amortized solve) but with no staging LDS: each lane
// loads its 8(+tail) points once from global, moments are accumulated, and
// the 54 point-floats are PINNED in VGPRs across the solve (asm "+v") so the
// residual pass reads registers -- the second 209MB pass through LDS/TA that
// R11/R13 paid is gone. LDS = 2KB tiles; 4 blocks/CU = 16 waves/CU.
__global__ __launch_bounds__(256, 4) void pa_mpjpe_kernel(
    const float* __restrict__ outp,   // (N,K,3) output
    const float* __restrict__ tgtp,   // (N,K,3) target
    float* __restrict__ block_sums,
    int nsamp)
{
    const int tid  = threadIdx.x;
    const int lane = tid & 63;
    const int wid  = tid >> 6;
    const int l16  = lane & 15;
    const int s_l  = wid * SPWV + (lane >> 4);   // local sample 0..15
    int s = blockIdx.x * SPB + s_l;
    const bool valid = (s < nsamp);
    if (!valid) s = 0;                           // clamp; zeroed later

    __shared__ float momT[SPB][17];
    __shared__ float prm[SPB][13];
    __shared__ float shs[SPB];

    const float* tb = tgtp + (size_t)s * FPS;
    const float* ob = outp + (size_t)s * FPS;

    // ---- declare + load points (named scalars), accumulate moments ----
    float2 P0 = f2(0,0), P1 = f2(0,0), P2 = f2(0,0), P3 = f2(0,0);
    float2 P4 = f2(0,0), P5 = f2(0,0), P6 = f2(0,0), P7 = f2(0,0);
    float2 Q  = f2(0,0);

#define DECLPT(k) float t0_##k=0.f,t1_##k=0.f,t2_##k=0.f,o0_##k=0.f,o1_##k=0.f,o2_##k=0.f;
#define LOADPT(k, P) { const int idx_ = 3*(P);                              \
    t0_##k=tb[idx_+0]; t1_##k=tb[idx_+1]; t2_##k=tb[idx_+2];                \
    o0_##k=ob[idx_+0]; o1_##k=ob[idx_+1]; o2_##k=ob[idx_+2]; }
#define ACCPT(k)                                                            \
    P0 += f2(t0_##k, t1_##k);                                               \
    P1 += f2(t2_##k, o0_##k);                                               \
    P2 += f2(o1_##k, o2_##k);                                               \
    P3 += f2(t0_##k, t0_##k) * f2(o0_##k, o1_##k);                          \
    P4 += f2(t0_##k, t1_##k) * f2(o2_##k, o0_##k);                          \
    P5 += f2(t1_##k, t1_##k) * f2(o1_##k, o2_##k);                          \
    P6 += f2(t2_##k, t2_##k) * f2(o0_##k, o1_##k);                          \
    P7 += f2(t2_##k, t0_##k) * f2(o2_##k, t0_##k);                          \
    Q  += f2(t1_##k, t2_##k) * f2(t1_##k, t2_##k);
#define PINPT(k) PIN(t0_##k); PIN(t1_##k); PIN(t2_##k); \
                 PIN(o0_##k); PIN(o1_##k); PIN(o2_##k);

    DECLPT(0) DECLPT(1) DECLPT(2) DECLPT(3)
    DECLPT(4) DECLPT(5) DECLPT(6) DECLPT(7)
    DECLPT(8)

    LOADPT(0, l16 +   0)  ACCPT(0)
    LOADPT(1, l16 +  16)  ACCPT(1)
    LOADPT(2, l16 +  32)  ACCPT(2)
    LOADPT(3, l16 +  48)  ACCPT(3)
    LOADPT(4, l16 +  64)  ACCPT(4)
    LOADPT(5, l16 +  80)  ACCPT(5)
    LOADPT(6, l16 +  96)  ACCPT(6)
    LOADPT(7, l16 + 112)  ACCPT(7)
    if (l16 < 5) {
        LOADPT(8, 128 + l16)  ACCPT(8)
    }

    // pin all point registers: live across butterfly + solve + barriers
    PINPT(0) PINPT(1) PINPT(2) PINPT(3)
    PINPT(4) PINPT(5) PINPT(6) PINPT(7)
    PINPT(8)

    float red[16];
    red[0]  = P0.x; red[1]  = P0.y; red[2]  = P1.x; red[3]  = P1.y;
    red[4]  = P2.x; red[5]  = P2.y; red[6]  = P3.x; red[7]  = P3.y;
    red[8]  = P4.x; red[9]  = P4.y; red[10] = P5.x; red[11] = P5.y;
    red[12] = P6.x; red[13] = P6.y; red[14] = P7.x; red[15] = P7.y + Q.x + Q.y;

    // ---- 4-stage value-splitting butterfly within 16-lane group ----
    float v8[8];
    {
        const bool b = (lane & 1);
        #pragma unroll
        for (int m = 0; m < 8; ++m) {
            const float snd = b ? red[2 * m] : red[2 * m + 1];
            const float rcv = DPP_XOR1(snd);
            v8[m] = (b ? red[2 * m + 1] : red[2 * m]) + rcv;
        }
    }
    float v4_[4];
    {
        const bool b = ((lane >> 1) & 1);
        #pragma unroll
        for (int m = 0; m < 4; ++m) {
            const float snd = b ? v8[2 * m] : v8[2 * m + 1];
            const float rcv = DPP_XOR2(snd);
            v4_[m] = (b ? v8[2 * m + 1] : v8[2 * m]) + rcv;
        }
    }
    float v2_[2];
    {
        const bool b = ((lane >> 2) & 1);
        #pragma unroll
        for (int m = 0; m < 2; ++m) {
            const float snd = b ? v4_[2 * m] : v4_[2 * m + 1];
            const float rcv = __shfl_xor(snd, 4, 64);
            v2_[m] = (b ? v4_[2 * m + 1] : v4_[2 * m]) + rcv;
        }
    }
    float v1;
    {
        const bool b = ((lane >> 3) & 1);
        const float snd = b ? v2_[0] : v2_[1];
        const float rcv = __shfl_xor(snd, 8, 64);
        v1 = (b ? v2_[1] : v2_[0]) + rcv;
    }

    momT[s_l][l16] = v1;
    __syncthreads();

    // ---- solve: wave 0, lanes 0..15, one sample each (16x amortized) ----
    if (wid == 0 && lane < SPB && (blockIdx.x * SPB + lane) < nsamp) {
        float m_[16];
        #pragma unroll
        for (int j = 0; j < 16; ++j) m_[j] = momT[lane][j];

        const float invK = 1.0f / (float)KPTS;
        const float mu1x = m_[0] * invK, mu1y = m_[1] * invK, mu1z = m_[2] * invK;
        const float mu2x = m_[3] * invK, mu2y = m_[4] * invK, mu2z = m_[5] * invK;

        const float Sxx = m_[6]  - m_[0] * m_[3] * invK;
        const float Sxy = m_[7]  - m_[0] * m_[4] * invK;
        const float Sxz = m_[8]  - m_[0] * m_[5] * invK;
        const float Syx = m_[9]  - m_[1] * m_[3] * invK;
        const float Syy = m_[10] - m_[1] * m_[4] * invK;
        const float Syz = m_[11] - m_[1] * m_[5] * invK;
        const float Szx = m_[12] - m_[2] * m_[3] * invK;
        const float Szy = m_[13] - m_[2] * m_[4] * invK;
        const float Szz = m_[14] - m_[2] * m_[5] * invK;
        const float var1 = m_[15] - (m_[0] * m_[0] + m_[1] * m_[1] + m_[2] * m_[2]) * invK;

        const float N00 = Sxx + Syy + Szz;
        const float N01 = Syz - Szy, N02 = Szx - Sxz, N03 = Sxy - Syx;
        const float N11 = Sxx - Syy - Szz, N12 = Sxy + Syx, N13 = Szx + Sxz;
        const float N22 = -Sxx + Syy - Szz, N23 = Syz + Szy;
        const float N33 = -Sxx - Syy + Szz;

        const float trKtK = Sxx * Sxx + Sxy * Sxy + Sxz * Sxz
                          + Syx * Syx + Syy * Syy + Syz * Syz
                          + Szx * Szx + Szy * Szy + Szz * Szz;
        const float c2 = -2.0f * trKtK;
        const float detK = det3(Sxx, Sxy, Sxz, Syx, Syy, Syz, Szx, Szy, Szz);
        const float c1 = -8.0f * detK;
        const float c0 =
              N00 * det3(N11, N12, N13, N12, N22, N23, N13, N23, N33)
            - N01 * det3(N01, N12, N13, N02, N22, N23, N03, N23, N33)
            + N02 * det3(N01, N11, N13, N02, N12, N23, N03, N13, N33)
            - N03 * det3(N01, N11, N12, N02, N12, N22, N03, N13, N23);

        float lam = sqrtf(fmaxf(3.0f * trKtK, 0.0f));
        #pragma unroll
        for (int it = 0; it < 10; ++it) {
            const float l2 = lam * lam;
            const float P  = (l2 + c2) * l2 + c1 * lam + c0;
            const float Pp = (4.0f * l2 + 2.0f * c2) * lam + c1;
            lam -= P / Pp;
        }

        const float M00 = N00 - lam, M11 = N11 - lam, M22 = N22 - lam, M33 = N33 - lam;
        const float a0 =  det3(M11, N12, N13, N12, M22, N23, N13, N23, M33);
        const float a1 = -det3(N01, N12, N13, N02, M22, N23, N03, N23, M33);
        const float a2 =  det3(N01, M11, N13, N02, N12, N23, N03, N13, M33);
        const float a3 = -det3(N01, M11, N12, N02, N12, M22, N03, N13, N23);
        const float b0 = -det3(N01, N02, N03, N12, M22, N23, N13, N23, M33);
        const float b1 =  det3(M00, N02, N03, N02, M22, N23, N03, N23, M33);
        const float b2 = -det3(M00, N01, N03, N02, N12, N23, N03, N13, M33);
        const float b3 =  det3(M00, N01, N02, N02, N12, M22, N03, N13, N23);
        const float na = a0 * a0 + a1 * a1 + a2 * a2 + a3 * a3;
        const float nb = b0 * b0 + b1 * b1 + b2 * b2 + b3 * b3;
        const bool pa_ = (na >= nb);
        float qw = pa_ ? a0 : b0;
        float qx = pa_ ? a1 : b1;
        float qy = pa_ ? a2 : b2;
        float qz = pa_ ? a3 : b3;
        const float qn = rsqrtf(fmaxf(qw * qw + qx * qx + qy * qy + qz * qz, 1e-30f));
        qw *= qn; qx *= qn; qy *= qn; qz *= qn;

        const float R00 = 1.0f - 2.0f * (qy * qy + qz * qz);
        const float R01 = 2.0f * (qx * qy - qw * qz);
        const float R02 = 2.0f * (qx * qz + qw * qy);
        const float R10 = 2.0f * (qx * qy + qw * qz);
        const float R11 = 1.0f - 2.0f * (qx * qx + qz * qz);
        const float R12 = 2.0f * (qy * qz - qw * qx);
        const float R20 = 2.0f * (qx * qz - qw * qy);
        const float R21 = 2.0f * (qy * qz + qw * qx);
        const float R22 = 1.0f - 2.0f * (qx * qx + qy * qy);

        const float trRK = R00 * Sxx + R01 * Syx + R02 * Szx
                         + R10 * Sxy + R11 * Syy + R12 * Szy
                         + R20 * Sxz + R21 * Syz + R22 * Szz;
        const float scale = trRK / var1;

        const float tx = mu2x - scale * (R00 * mu1x + R01 * mu1y + R02 * mu1z);
        const float ty = mu2y - scale * (R10 * mu1x + R11 * mu1y + R12 * mu1z);
        const float tz = mu2z - scale * (R20 * mu1x + R21 * mu1y + R22 * mu1z);

        prm[lane][0] = scale * R00; prm[lane][1] = scale * R01; prm[lane][2] = scale * R02;
        prm[lane][3] = scale * R10; prm[lane][4] = scale * R11; prm[lane][5] = scale * R12;
        prm[lane][6] = scale * R20; prm[lane][7] = scale * R21; prm[lane][8] = scale * R22;
        prm[lane][9] = tx; prm[lane][10] = ty; prm[lane][11] = tz;
    }
    __syncthreads();

    // ---- residuals from PINNED registers (no second data pass) ----
    const float2 rA = f2(prm[s_l][0], prm[s_l][3]);   // (sR00, sR10)
    const float2 rB = f2(prm[s_l][1], prm[s_l][4]);   // (sR01, sR11)
    const float2 rC = f2(prm[s_l][2], prm[s_l][5]);   // (sR02, sR12)
    const float sR20 = prm[s_l][6], sR21 = prm[s_l][7], sR22 = prm[s_l][8];
    const float2 txy = f2(prm[s_l][9], prm[s_l][10]);
    const float tz = prm[s_l][11];

    float rsum = 0.0f;
#define RESPT(k)                                                            \
    {                                                                       \
        float2 axy = txy;                                                   \
        axy += rA * f2(t0_##k, t0_##k);                                     \
        axy += rB * f2(t1_##k, t1_##k);                                     \
        axy += rC * f2(t2_##k, t2_##k);                                     \
        const float az = fmaf(sR20, t0_##k, fmaf(sR21, t1_##k, fmaf(sR22, t2_##k, tz))); \
        const float2 dxy = f2(o0_##k, o1_##k) - axy;                        \
        const float dz = o2_##k - az;                                       \
        const float ns = fmaf(dxy.x, dxy.x, fmaf(dxy.y, dxy.y, dz * dz));   \
        rsum += sqrtf(ns);                                                  \
    }

    RESPT(0) RESPT(1) RESPT(2) RESPT(3)
    RESPT(4) RESPT(5) RESPT(6) RESPT(7)
    if (l16 < 5) { RESPT(8) }

    rsum = valid ? rsum : 0.0f;

    rsum += DPP_XOR1(rsum);
    rsum += DPP_XOR2(rsum);
    rsum += __shfl_xor(rsum, 4, 64);
    rsum += __shfl_xor(rsum, 8, 64);

    if (l16 == 0) shs[s_l] = rsum;
    __syncthreads();
    if (tid == 0) {
        float b = 0.0f;
        #pragma unroll
        for (int i = 0; i < SPB; ++i) b += shs[i];
        block_sums[blockIdx.x] = b;
    }
}

// Deterministic final reduction: one block, fixed order, 4-way ILP.
__global__ __launch_bounds__(256) void pa_reduce_kernel(
    const float* __restrict__ block_sums, int n,
    float* __restrict__ out, float inv_total)
{
    __shared__ float sh[4];
    float a0 = 0.f, a1 = 0.f, a2 = 0.f, a3 = 0.f;
    for (int i = (int)threadIdx.x * 4; i < n; i += 1024) {
        if (i + 0 < n) a0 += block_sums[i + 0];
        if (i + 1 < n) a1 += block_sums[i + 1];
        if (i + 2 < n) a2 += block_sums[i + 2];
        if (i + 3 < n) a3 += block_sums[i + 3];
    }
    float v = (a0 + a1) + (a2 + a3);
    #pragma unroll
    for (int off = 32; off >= 1; off >>= 1) v += __shfl_xor(v, off, 64);
    const int lane = threadIdx.x & 63;
    const int wid  = threadIdx.x >> 6;
    if (lane == 0) sh[wid] = v;
    __syncthreads();
    if (threadIdx.x == 0) out[0] = (sh[0] + sh[1] + sh[2] + sh[3]) * inv_total;
}

extern "C" void kernel_launch(void* const* d_in, const int* in_sizes, int n_in,
                              void* d_out, int out_size, void* d_ws, size_t ws_size,
                              hipStream_t stream) {
    const float* outp = (const float*)d_in[0];   // "output"
    const float* tgtp = (const float*)d_in[1];   // "target"
    const int nsamp   = in_sizes[0] / FPS;
    const int nblocks = (nsamp + SPB - 1) / SPB;

    float* bsums = (float*)d_ws;

    pa_mpjpe_kernel<<<nblocks, 256, 0, stream>>>(outp, tgtp, bsums, nsamp);
    pa_reduce_kernel<<<1, 256, 0, stream>>>(
        bsums, nblocks, (float*)d_out,
        1.0f / ((float)nsamp * (float)KPTS));
}